// Round 6
// baseline (225.832 us; speedup 1.0000x reference)
//
#include <hip/hip_runtime.h>

#define SGRID 28
#define NBATCH 1024
constexpr int CELLS = NBATCH * SGRID * SGRID;   // 802816
constexpr int TPW   = 2;                        // tiles per wave (64 cells/tile)
constexpr int NWAVE = CELLS / (64 * TPW);       // 6272 waves
constexpr int NBLK  = NWAVE / 4;                // 1568 blocks x 4 waves
constexpr float L_COORD = 5.0f;
constexpr float L_NOOBJ = 0.5f;

__global__ __launch_bounds__(256, 5) void yolo_main(
    const float* __restrict__ pred,      // CELLS*30
    const float* __restrict__ tboxes,    // CELLS*4
    const float* __restrict__ tcls,      // CELLS*20
    const int*   __restrict__ objmap,    // CELLS
    float4* __restrict__ partials)       // NWAVE partials {reg, cobj, nbj, cls}
{
    __shared__ float sp[4][64 * 30];     // 7680 B per wave, wave-private: NO barriers
    const int lane = threadIdx.x & 63;
    const int wv   = threadIdx.x >> 6;
    float* buf = sp[wv];
    const int gw    = blockIdx.x * 4 + wv;   // global wave id
    const int tile0 = gw * TPW;

    // ---- cross-tile prefetch registers ----
    float4 pn[8], tbn;
    float  fmn;
    auto pre = [&](int tile) {
        const float4* p4 = reinterpret_cast<const float4*>(pred + (size_t)tile * 64 * 30);
        #pragma unroll
        for (int i = 0; i < 7; ++i) pn[i] = p4[lane + i * 64];
        if (lane < 32) pn[7] = p4[448 + lane];
        tbn = reinterpret_cast<const float4*>(tboxes)[tile * 64 + lane];
        fmn = (objmap[tile * 64 + lane] != 0) ? 1.f : 0.f;
    };
    pre(tile0);

    float accr = 0.f, accc = 0.f, accn = 0.f, accl = 0.f;

    #pragma unroll
    for (int t = 0; t < TPW; ++t) {
        float4 tbv = tbn;                // latch current tile scalars
        float  fm  = fmn;

        // stage current pred slab to wave-private LDS (in-order DS, no barrier)
        float4* b4 = reinterpret_cast<float4*>(buf);
        #pragma unroll
        for (int i = 0; i < 7; ++i) b4[lane + i * 64] = pn[i];
        if (lane < 32) b4[448 + lane] = pn[7];

        // issue current tcls loads + next tile's prefetch: in flight over compute
        float4 tn[5];
        const float4* tc4 = reinterpret_cast<const float4*>(tcls) + (size_t)(tile0 + t) * 64 * 5;
        #pragma unroll
        for (int i = 0; i < 5; ++i) tn[i] = tc4[lane + i * 64];
        if (t + 1 < TPW) pre(tile0 + t + 1);

        __builtin_amdgcn_wave_barrier(); // scheduling fence only; DS is wave-ordered

        // ---- box math: lane = cell (LDS stride 30 -> 2-way alias, free) ----
        const float* q = buf + lane * 30;
        {
            const float invS = 1.0f / SGRID;
            float tx = tbv.x * invS, ty = tbv.y * invS;
            float thw = 0.5f * tbv.z, thh = 0.5f * tbv.w;
            float tx1 = tx - thw, ty1 = ty - thh, tx2 = tx + thw, ty2 = ty + thh;
            float ta = (tx2 - tx1) * (ty2 - ty1);

            float bx1[2], by1[2], bx2[2], by2[2], bcf[2], biou[2];
            #pragma unroll
            for (int b = 0; b < 2; ++b) {
                float cx = q[b*5+0] * invS, cy = q[b*5+1] * invS;
                float hw = 0.5f * q[b*5+2], hh = 0.5f * q[b*5+3];
                float x1 = cx - hw, y1 = cy - hh, x2 = cx + hw, y2 = cy + hh;
                bx1[b] = x1; by1[b] = y1; bx2[b] = x2; by2[b] = y2; bcf[b] = q[b*5+4];
                float ltx = fmaxf(x1, tx1), lty = fmaxf(y1, ty1);
                float rbx = fminf(x2, tx2), rby = fminf(y2, ty2);
                float wi = fmaxf(rbx - ltx, 0.f), hi = fmaxf(rby - lty, 0.f);
                float inter = wi * hi;
                float a1 = (x2 - x1) * (y2 - y1);
                biou[b] = inter / (a1 + ta - inter);
            }
            int sel = (biou[1] > biou[0]) ? 1 : 0;
            float best_iou = biou[sel];
            bool valid = best_iou > 0.f;
            float bbx1 = valid ? bx1[sel] : 0.f;
            float bby1 = valid ? by1[sel] : 0.f;
            float bbx2 = valid ? bx2[sel] : 0.f;
            float bby2 = valid ? by2[sel] : 0.f;
            float bcfs = valid ? bcf[sel] : 0.f;
            best_iou   = valid ? best_iou : 0.f;

            float dx = bbx1 - tx1, dy = bby1 - ty1;
            float lxy = dx * dx + dy * dy;
            auto ssqrt = [](float x) { return x > 0.f ? sqrtf(x) : 0.f; };
            float dwx = ssqrt(bbx2) - ssqrt(tx2);
            float dwy = ssqrt(bby2) - ssqrt(ty2);
            float lwh = dwx * dwx + dwy * dwy;
            accr += fm * (lxy + lwh);

            float c0 = q[4], c1 = q[9];
            accn += (1.f - fm) * (c0 * c0 + c1 * c1);

            float dc = bcfs - best_iou;
            accc += fm * dc * dc;
        }

        // ---- cls loss: pred from LDS, tcls from regs, mask via shuffle ----
        #pragma unroll
        for (int i = 0; i < 5; ++i) {
            int e = lane + i * 64;       // [0, 320) flat float4 over tile's tcls
            float4 tcv = tn[i];
            int cell = e / 5;            // [0, 64) — within this wave
            int c0   = (e - cell * 5) * 4;
            const float* pc = buf + cell * 30 + 10 + c0;
            float mk = __shfl(fm, cell);
            float d0 = pc[0] - tcv.x, d1 = pc[1] - tcv.y;
            float d2 = pc[2] - tcv.z, d3 = pc[3] - tcv.w;
            accl += mk * (d0 * d0 + d1 * d1 + d2 * d2 + d3 * d3);
        }
    }

    // ---- per-wave reduction, one float4 store per wave ----
    #pragma unroll
    for (int off = 32; off > 0; off >>= 1) {
        accr += __shfl_down(accr, off);
        accc += __shfl_down(accc, off);
        accn += __shfl_down(accn, off);
        accl += __shfl_down(accl, off);
    }
    if (lane == 0) partials[gw] = make_float4(accr, accc, accn, accl);
}

__global__ __launch_bounds__(1024) void yolo_finalize(
    const float4* __restrict__ partials, float* __restrict__ out)
{
    float4 s = {0.f, 0.f, 0.f, 0.f};
    for (int b = threadIdx.x; b < NWAVE; b += 1024) {
        float4 v = partials[b];
        s.x += v.x; s.y += v.y; s.z += v.z; s.w += v.w;
    }
    #pragma unroll
    for (int off = 32; off > 0; off >>= 1) {
        s.x += __shfl_down(s.x, off);
        s.y += __shfl_down(s.y, off);
        s.z += __shfl_down(s.z, off);
        s.w += __shfl_down(s.w, off);
    }
    __shared__ float4 sw[16];
    int wave = threadIdx.x >> 6, lane = threadIdx.x & 63;
    if (lane == 0) sw[wave] = s;
    __syncthreads();
    if (threadIdx.x == 0) {
        float r = 0.f, c = 0.f, n = 0.f, cl = 0.f;
        #pragma unroll
        for (int w = 0; w < 16; ++w) {
            r += sw[w].x; c += sw[w].y; n += sw[w].z; cl += sw[w].w;
        }
        const float invN = 1.0f / NBATCH;
        float reg_l  = L_COORD * r * invN;
        float cobj_l = c * invN;
        float nbj_l  = L_NOOBJ * n * invN;
        float cls_l  = 2.0f * cl * invN;
        out[0] = cls_l + nbj_l + reg_l + cobj_l;
        out[1] = reg_l;
        out[2] = cobj_l;
        out[3] = nbj_l;
        out[4] = cls_l;
    }
}

extern "C" void kernel_launch(void* const* d_in, const int* in_sizes, int n_in,
                              void* d_out, int out_size, void* d_ws, size_t ws_size,
                              hipStream_t stream) {
    const float* pred   = (const float*)d_in[0];
    const float* tboxes = (const float*)d_in[1];
    const float* tcls   = (const float*)d_in[2];
    const int*   objmap = (const int*)d_in[3];
    float4* partials = (float4*)d_ws;
    float*  out      = (float*)d_out;

    yolo_main<<<NBLK, 256, 0, stream>>>(pred, tboxes, tcls, objmap, partials);
    yolo_finalize<<<1, 1024, 0, stream>>>(partials, out);
}

// Round 7
// 218.996 us; speedup vs baseline: 1.0312x; 1.0312x over previous
//
#include <hip/hip_runtime.h>

#define SGRID 28
#define NBATCH 1024
constexpr int CELLS = NBATCH * SGRID * SGRID;   // 802816
constexpr int W     = 16;                       // tiles per wave (8 cells/tile)
constexpr int NWAVE = CELLS / (8 * W);          // 6272 waves (128 cells each)
constexpr int NBLK  = NWAVE / 4;                // 1568 blocks x 4 waves
constexpr float L_COORD = 5.0f;
constexpr float L_NOOBJ = 0.5f;

struct TR {                       // per-lane tile registers (no arrays -> no scratch)
    float2 q0, q1;                // pred floats [4s,4s+1], [4s+2,4s+3]
    float4 tc;                    // tcls floats [4s..4s+3]   (subl<5)
    float2 tb0, tb1;              // tbox xy, wh              (subl==7)
    float  fm;                    // mask                     (subl==7)
};

__device__ __forceinline__ TR load_tile(
    const float* __restrict__ pred, const float* __restrict__ tboxes,
    const float* __restrict__ tcls, const int* __restrict__ objmap,
    int tile, int grp, int subl)
{
    TR r;
    const int c = tile * 8 + grp;
    const float* pb = pred + (size_t)c * 30 + subl * 4;
    r.q0 = *reinterpret_cast<const float2*>(pb);          // 8B-aligned always
    if (subl < 7) r.q1 = *reinterpret_cast<const float2*>(pb + 2);
    else          r.q1 = make_float2(0.f, 0.f);
    if (subl < 5) r.tc = *reinterpret_cast<const float4*>(tcls + (size_t)c * 20 + subl * 4);
    else          r.tc = make_float4(0.f, 0.f, 0.f, 0.f);
    if (subl == 7) {
        float4 t = reinterpret_cast<const float4*>(tboxes)[c];
        r.tb0 = make_float2(t.x, t.y);
        r.tb1 = make_float2(t.z, t.w);
        r.fm  = (objmap[c] != 0) ? 1.f : 0.f;
    } else { r.tb0 = make_float2(0.f, 0.f); r.tb1 = make_float2(0.f, 0.f); r.fm = 0.f; }
    return r;
}

__global__ __launch_bounds__(256) void yolo_main(
    const float* __restrict__ pred,      // CELLS*30
    const float* __restrict__ tboxes,    // CELLS*4
    const float* __restrict__ tcls,      // CELLS*20
    const int*   __restrict__ objmap,    // CELLS
    float4* __restrict__ partials)       // NWAVE partials {reg, cobj, nbj, cls}
{
    const int lane = threadIdx.x & 63;
    const int wv   = threadIdx.x >> 6;
    const int gw   = blockIdx.x * 4 + wv;    // global wave id
    const int subl = lane & 7;
    const int grp  = lane >> 3;
    const int gb   = lane & 56;              // group base lane
    const int tile0 = gw * W;

    float accr = 0.f, accc = 0.f, accn = 0.f, accl = 0.f;

    TR cur = load_tile(pred, tboxes, tcls, objmap, tile0, grp, subl);
    TR nxt;

    #pragma unroll 1
    for (int t = 0; t < W; ++t) {
        // issue next tile's loads; they stay in flight over this tile's compute
        if (t + 1 < W) nxt = load_tile(pred, tboxes, tcls, objmap, tile0 + t + 1, grp, subl);
        else           nxt = cur;

        // ---- gather own group's box floats f0..f9 + tbox + mask via shuffles ----
        float f0 = __shfl(cur.q0.x, gb + 0), f1 = __shfl(cur.q0.y, gb + 0);
        float f2 = __shfl(cur.q1.x, gb + 0), f3 = __shfl(cur.q1.y, gb + 0);
        float f4 = __shfl(cur.q0.x, gb + 1), f5 = __shfl(cur.q0.y, gb + 1);
        float f6 = __shfl(cur.q1.x, gb + 1), f7 = __shfl(cur.q1.y, gb + 1);
        float f8 = __shfl(cur.q0.x, gb + 2), f9 = __shfl(cur.q0.y, gb + 2);
        float tbx = __shfl(cur.tb0.x, gb + 7), tby = __shfl(cur.tb0.y, gb + 7);
        float tbz = __shfl(cur.tb1.x, gb + 7), tbw = __shfl(cur.tb1.y, gb + 7);
        float fmv = __shfl(cur.fm, gb + 7);

        // ---- box math (duplicated across the 8 group lanes; only subl==0 accumulates) ----
        {
            const float invS = 1.0f / SGRID;
            float tx = tbx * invS, ty = tby * invS;
            float thw = 0.5f * tbz, thh = 0.5f * tbw;
            float tx1 = tx - thw, ty1 = ty - thh, tx2 = tx + thw, ty2 = ty + thh;
            float ta = (tx2 - tx1) * (ty2 - ty1);

            float px[2] = {f0, f5}, py[2] = {f1, f6}, pw[2] = {f2, f7},
                  ph[2] = {f3, f8}, pc[2] = {f4, f9};
            float bx1[2], by1[2], bx2[2], by2[2], biou[2];
            #pragma unroll
            for (int b = 0; b < 2; ++b) {
                float cx = px[b] * invS, cy = py[b] * invS;
                float hw = 0.5f * pw[b], hh = 0.5f * ph[b];
                float x1 = cx - hw, y1 = cy - hh, x2 = cx + hw, y2 = cy + hh;
                bx1[b] = x1; by1[b] = y1; bx2[b] = x2; by2[b] = y2;
                float ltx = fmaxf(x1, tx1), lty = fmaxf(y1, ty1);
                float rbx = fminf(x2, tx2), rby = fminf(y2, ty2);
                float wi = fmaxf(rbx - ltx, 0.f), hi = fmaxf(rby - lty, 0.f);
                float inter = wi * hi;
                float a1 = (x2 - x1) * (y2 - y1);
                biou[b] = inter / (a1 + ta - inter);
            }
            int sel = (biou[1] > biou[0]) ? 1 : 0;
            float best_iou = biou[sel];
            bool valid = best_iou > 0.f;
            float bbx1 = valid ? bx1[sel] : 0.f;
            float bby1 = valid ? by1[sel] : 0.f;
            float bbx2 = valid ? bx2[sel] : 0.f;
            float bby2 = valid ? by2[sel] : 0.f;
            float bcfs = valid ? pc[sel]  : 0.f;
            best_iou   = valid ? best_iou : 0.f;

            float dx = bbx1 - tx1, dy = bby1 - ty1;
            float lxy = dx * dx + dy * dy;
            auto ssqrt = [](float x) { return x > 0.f ? sqrtf(x) : 0.f; };
            float dwx = ssqrt(bbx2) - ssqrt(tx2);
            float dwy = ssqrt(bby2) - ssqrt(ty2);
            float lwh = dwx * dwx + dwy * dwy;
            float dc  = bcfs - best_iou;

            if (subl == 0) {
                accr += fmv * (lxy + lwh);
                accn += (1.f - fmv) * (pc[0] * pc[0] + pc[1] * pc[1]);
                accc += fmv * dc * dc;
            }
        }

        // ---- cls loss: lane subl(0..4) owns tcls[4s..4s+3]; gather matching pred ----
        {
            float pz = __shfl(cur.q1.x, gb + 2 + subl);  // pred f[10+4s]
            float pw = __shfl(cur.q1.y, gb + 2 + subl);  // pred f[11+4s]
            float qx = __shfl(cur.q0.x, gb + 3 + subl);  // pred f[12+4s]
            float qy = __shfl(cur.q0.y, gb + 3 + subl);  // pred f[13+4s]
            if (subl < 5) {
                float d0 = pz - cur.tc.x, d1 = pw - cur.tc.y;
                float d2 = qx - cur.tc.z, d3 = qy - cur.tc.w;
                accl += fmv * (d0 * d0 + d1 * d1 + d2 * d2 + d3 * d3);
            }
        }

        cur = nxt;
    }

    // ---- per-wave reduction, one float4 store per wave ----
    #pragma unroll
    for (int off = 32; off > 0; off >>= 1) {
        accr += __shfl_down(accr, off);
        accc += __shfl_down(accc, off);
        accn += __shfl_down(accn, off);
        accl += __shfl_down(accl, off);
    }
    if (lane == 0) partials[gw] = make_float4(accr, accc, accn, accl);
}

__global__ __launch_bounds__(1024) void yolo_finalize(
    const float4* __restrict__ partials, float* __restrict__ out)
{
    float4 s = {0.f, 0.f, 0.f, 0.f};
    for (int b = threadIdx.x; b < NWAVE; b += 1024) {
        float4 v = partials[b];
        s.x += v.x; s.y += v.y; s.z += v.z; s.w += v.w;
    }
    #pragma unroll
    for (int off = 32; off > 0; off >>= 1) {
        s.x += __shfl_down(s.x, off);
        s.y += __shfl_down(s.y, off);
        s.z += __shfl_down(s.z, off);
        s.w += __shfl_down(s.w, off);
    }
    __shared__ float4 sw[16];
    int wave = threadIdx.x >> 6, lane = threadIdx.x & 63;
    if (lane == 0) sw[wave] = s;
    __syncthreads();
    if (threadIdx.x == 0) {
        float r = 0.f, c = 0.f, n = 0.f, cl = 0.f;
        #pragma unroll
        for (int w = 0; w < 16; ++w) {
            r += sw[w].x; c += sw[w].y; n += sw[w].z; cl += sw[w].w;
        }
        const float invN = 1.0f / NBATCH;
        float reg_l  = L_COORD * r * invN;
        float cobj_l = c * invN;
        float nbj_l  = L_NOOBJ * n * invN;
        float cls_l  = 2.0f * cl * invN;
        out[0] = cls_l + nbj_l + reg_l + cobj_l;
        out[1] = reg_l;
        out[2] = cobj_l;
        out[3] = nbj_l;
        out[4] = cls_l;
    }
}

extern "C" void kernel_launch(void* const* d_in, const int* in_sizes, int n_in,
                              void* d_out, int out_size, void* d_ws, size_t ws_size,
                              hipStream_t stream) {
    const float* pred   = (const float*)d_in[0];
    const float* tboxes = (const float*)d_in[1];
    const float* tcls   = (const float*)d_in[2];
    const int*   objmap = (const int*)d_in[3];
    float4* partials = (float4*)d_ws;
    float*  out      = (float*)d_out;

    yolo_main<<<NBLK, 256, 0, stream>>>(pred, tboxes, tcls, objmap, partials);
    yolo_finalize<<<1, 1024, 0, stream>>>(partials, out);
}